// Round 8
// baseline (177.335 us; speedup 1.0000x reference)
//
#include <hip/hip_runtime.h>
#include <math.h>

#define NUM_FREQS 10
#define EDIM 60            // 3 * 2 * NUM_FREQS
#define TRADEOFF 1.0f

typedef __attribute__((ext_vector_type(8))) short bf16x8;
typedef __attribute__((ext_vector_type(4))) float f32x4;

#define MFMA(a, b, c) __builtin_amdgcn_mfma_f32_16x16x32_bf16((a), (b), (c), 0, 0, 0)

// float -> bf16 (RNE) native cast
__device__ __forceinline__ short bfc(float f) {
    return __builtin_bit_cast(short, (__bf16)f);
}
// xor16 lane exchange via ds_swizzle (BitMode: offset = (xor<<10)|(or<<5)|and)
__device__ __forceinline__ float swz16(float x) {
    return __builtin_bit_cast(float,
        __builtin_amdgcn_ds_swizzle(__builtin_bit_cast(int, x), 0x401F));
}
// xor32 (crosses 32-lane halves)
__device__ __forceinline__ float sx32(float x) { return __shfl_xor(x, 32, 64); }

// Full posenc (prologue only, for centroids). Hardware sin/cos in revolutions.
__device__ __forceinline__ void posenc3(float x0, float x1, float x2, float* enc) {
    const float inv2pi = 0.15915494309189535f;
    float xs[3] = {x0, x1, x2};
#pragma unroll
    for (int d = 0; d < 3; ++d) {
        float xr = xs[d] * inv2pi;
#pragma unroll
        for (int l = 0; l < NUM_FREQS; ++l) {
            const float fr = __builtin_amdgcn_fractf(xr);
            enc[l*6 + d]     = __builtin_amdgcn_sinf(fr);
            enc[l*6 + 3 + d] = __builtin_amdgcn_cosf(fr);
            xr *= 2.0f;   // exact
        }
    }
}

// K-permutation: k' = 8b + 2i + c  (b = k-block 0..7, pair i 0..3, c: 0=sin 1=cos)
//   p = 4b + i (< 30), l = p/3, d = p%3  ->  original k = 6l + 3c + d.
// Blocks b=0..6 full; b=7 has pairs p=28,29 and 4 zero-pad elements (k'=60..63).
// This makes each lane's B-fragment (block b = kf*4+g) 4 (sin,cos) pairs of
// angles x_d * 2^l -- computable in-register with 1 fma + fract + v_sin/v_cos.
//
// sW rows r = 4c_cluster + ch (ch 0..2 = rgb channels, 3 = score row), columns
// in the k' basis, 16B-slot XOR swizzled. MFMA m-subtile tg -> lane (g,l15)
// acc[rg] = row 16tg+4g+rg = cluster 4tg+g, channel rg, point l15.
// Softmax (no max-sub: scores ~N(0,1), exp safe) accumulated online in-lane
// over 2 row-halves, then one cross-g butterfly (xor16 + xor32).
__global__ __launch_bounds__(256, 4) void fused4(
        const float* __restrict__ X,
        const int*   __restrict__ cluster_ids,
        const float* __restrict__ lm,      // [192, 60]
        const float* __restrict__ Wq,      // [5, 60]
        const float* __restrict__ Wk,      // [5, 60]
        const float* __restrict__ Wv,      // [3, 3]
        const float* __restrict__ cents,   // [64, 3]
        float* __restrict__ out,
        int N, int nChunks) {
    __shared__ __align__(16) unsigned short sW[256 * 64];  // 32 KB, k'-basis, swizzled

    const int tid  = threadIdx.x;
    const int lane = tid & 63;
    const int w    = tid >> 6;
    const int g    = (lane >> 4) & 3;
    const int l15  = lane & 15;

    // ================= prologue: build sW (once per block) =================
    {
        const int r = tid, ccl = r >> 2, ch = r & 3;
        float kq0 = 0.f, kq1 = 0.f, kq2 = 0.f, kq3 = 0.f, kq4 = 0.f;
        if (ch == 3) {
            float enc[EDIM];
            posenc3(cents[ccl*3+0], cents[ccl*3+1], cents[ccl*3+2], enc);
            const float isd = 0.4472135954999579f;  // 1/sqrt(5)
            float kk[5];
#pragma unroll
            for (int j = 0; j < 5; ++j) {
                float a = 0.f;
                for (int k = 0; k < EDIM; ++k) a = fmaf(enc[k], Wk[j*EDIM + k], a);
                kk[j] = a * isd;
            }
            kq0 = kk[0]; kq1 = kk[1]; kq2 = kk[2]; kq3 = kk[3]; kq4 = kk[4];
        }
        const float* lrow = lm + (3*ccl + (ch < 3 ? ch : 0)) * EDIM;
#pragma unroll
        for (int b = 0; b < 8; ++b) {
            bf16x8 v;
#pragma unroll
            for (int j = 0; j < 8; ++j) {
                const int p = b*4 + (j >> 1), cc = j & 1;
                float val = 0.f;
                if (p < 30) {
                    const int l = (p*11) >> 5, d = p - 3*l;
                    const int sig = 6*l + 3*cc + d;
                    if (ch < 3) val = lrow[sig];
                    else val = Wq[sig]*kq0 + Wq[60+sig]*kq1 + Wq[120+sig]*kq2
                             + Wq[180+sig]*kq3 + Wq[240+sig]*kq4;
                }
                v[j] = bfc(val);
            }
            *(bf16x8*)&sW[r*64 + (b ^ (r & 7))*8] = v;
        }
    }
    const float wv00 = Wv[0], wv01 = Wv[1], wv02 = Wv[2];
    const float wv10 = Wv[3], wv11 = Wv[4], wv12 = Wv[5];
    const float wv20 = Wv[6], wv21 = Wv[7], wv22 = Wv[8];

    __syncthreads();   // the ONLY block-wide barrier; sW read-only afterwards

    float* o_out = out;
    float* o_km  = out + (size_t)N * 3;
    float* o_at  = out + (size_t)N * 6;

    const float inv2pi = 0.15915494309189535f;
    const int slot0 = (g ^ (l15 & 7)) * 8;
    const int slot1 = ((4 + g) ^ (l15 & 7)) * 8;

    // ================= chunk loop (waves fully independent) =================
    for (int chunk = blockIdx.x; chunk < nChunks; chunk += gridDim.x) {
        const int base = (chunk << 8) + w*64;

#pragma unroll
        for (int h = 0; h < 2; ++h) {
            // ---- B-fragments for subtiles 2h, 2h+1, computed in-register
            bf16x8 bfr[2][2];
            int cid0, cid1, n0, n1;
#pragma unroll
            for (int u = 0; u < 2; ++u) {
                const int n = base + (2*h + u)*16 + l15;
                const int nc = n < N ? n : N - 1;
                if (u == 0) { n0 = n; cid0 = cluster_ids[nc]; }
                else        { n1 = n; cid1 = cluster_ids[nc]; }
                const float r0 = X[nc*3+0] * inv2pi;
                const float r1 = X[nc*3+1] * inv2pi;
                const float r2 = X[nc*3+2] * inv2pi;
#pragma unroll
                for (int kf = 0; kf < 2; ++kf) {
                    const int b = kf*4 + g;   // lane's k'-block
                    bf16x8 v;
#pragma unroll
                    for (int i = 0; i < 4; ++i) {
                        const int p = b*4 + i;
                        const int l = (p*11) >> 5;
                        const int d = p - 3*l;
                        const float rd = (d == 0) ? r0 : ((d == 1) ? r1 : r2);
                        const float t  = ldexpf(rd, l);
                        const float fr = __builtin_amdgcn_fractf(t);
                        const float sv = __builtin_amdgcn_sinf(fr);
                        const float cv = __builtin_amdgcn_cosf(fr);
                        const bool ok = (p < 30);
                        v[2*i]   = ok ? bfc(sv) : (short)0;
                        v[2*i+1] = ok ? bfc(cv) : (short)0;
                    }
                    bfr[u][kf] = v;
                }
            }

            // ---- online accumulators (no max-sub; scores are O(1))
            float S0=0.f, A00=0.f, A10=0.f, A20=0.f, K00=0.f, K10=0.f, K20=0.f;
            float S1=0.f, A01=0.f, A11=0.f, A21=0.f, K01=0.f, K11=0.f, K21=0.f;

#pragma unroll
            for (int half = 0; half < 2; ++half) {
                f32x4 acc[2][8];
#pragma unroll
                for (int t = 0; t < 8; ++t) {
                    const int row = (half*8 + t)*16 + l15;
                    const bf16x8 a0 = *(const bf16x8*)&sW[row*64 + slot0];
                    const bf16x8 a1 = *(const bf16x8*)&sW[row*64 + slot1];
                    const f32x4 z = (f32x4){0.f, 0.f, 0.f, 0.f};
                    acc[0][t] = MFMA(a1, bfr[0][1], MFMA(a0, bfr[0][0], z));
                    acc[1][t] = MFMA(a1, bfr[1][1], MFMA(a0, bfr[1][0], z));
                }
#pragma unroll
                for (int t = 0; t < 8; ++t) {
                    const int cl = 4*(half*8 + t) + g;   // this lane's cluster
                    {
                        const float e = __expf(acc[0][t][3]);
                        S0 += e;
                        A00 = fmaf(e, acc[0][t][0], A00);
                        A10 = fmaf(e, acc[0][t][1], A10);
                        A20 = fmaf(e, acc[0][t][2], A20);
                        const bool sel = (cid0 == cl);
                        K00 = sel ? acc[0][t][0] : K00;
                        K10 = sel ? acc[0][t][1] : K10;
                        K20 = sel ? acc[0][t][2] : K20;
                    }
                    {
                        const float e = __expf(acc[1][t][3]);
                        S1 += e;
                        A01 = fmaf(e, acc[1][t][0], A01);
                        A11 = fmaf(e, acc[1][t][1], A11);
                        A21 = fmaf(e, acc[1][t][2], A21);
                        const bool sel = (cid1 == cl);
                        K01 = sel ? acc[1][t][0] : K01;
                        K11 = sel ? acc[1][t][1] : K11;
                        K21 = sel ? acc[1][t][2] : K21;
                    }
                }
            }

            // ---- cross-g butterfly (xor16 swizzle + xor32 shfl), then store
            S0 += swz16(S0); A00 += swz16(A00); A10 += swz16(A10); A20 += swz16(A20);
            K00 += swz16(K00); K10 += swz16(K10); K20 += swz16(K20);
            S0 += sx32(S0);  A00 += sx32(A00);  A10 += sx32(A10);  A20 += sx32(A20);
            K00 += sx32(K00); K10 += sx32(K10); K20 += sx32(K20);

            S1 += swz16(S1); A01 += swz16(A01); A11 += swz16(A11); A21 += swz16(A21);
            K01 += swz16(K01); K11 += swz16(K11); K21 += swz16(K21);
            S1 += sx32(S1);  A01 += sx32(A01);  A11 += sx32(A11);  A21 += sx32(A21);
            K01 += sx32(K01); K11 += sx32(K11); K21 += sx32(K21);

            if (g == 0 && n0 < N) {
                const float inv = 1.0f / S0;
                const float u0 = A00*inv, u1 = A10*inv, u2 = A20*inv;
                const float at0 = wv00*u0 + wv01*u1 + wv02*u2;
                const float at1 = wv10*u0 + wv11*u1 + wv12*u2;
                const float at2 = wv20*u0 + wv21*u1 + wv22*u2;
                o_out[n0*3+0] = K00*TRADEOFF + at0*(1.0f - TRADEOFF);
                o_out[n0*3+1] = K10*TRADEOFF + at1*(1.0f - TRADEOFF);
                o_out[n0*3+2] = K20*TRADEOFF + at2*(1.0f - TRADEOFF);
                o_km[n0*3+0] = K00; o_km[n0*3+1] = K10; o_km[n0*3+2] = K20;
                o_at[n0*3+0] = at0; o_at[n0*3+1] = at1; o_at[n0*3+2] = at2;
            }
            if (g == 0 && n1 < N) {
                const float inv = 1.0f / S1;
                const float u0 = A01*inv, u1 = A11*inv, u2 = A21*inv;
                const float at0 = wv00*u0 + wv01*u1 + wv02*u2;
                const float at1 = wv10*u0 + wv11*u1 + wv12*u2;
                const float at2 = wv20*u0 + wv21*u1 + wv22*u2;
                o_out[n1*3+0] = K01*TRADEOFF + at0*(1.0f - TRADEOFF);
                o_out[n1*3+1] = K11*TRADEOFF + at1*(1.0f - TRADEOFF);
                o_out[n1*3+2] = K21*TRADEOFF + at2*(1.0f - TRADEOFF);
                o_km[n1*3+0] = K01; o_km[n1*3+1] = K11; o_km[n1*3+2] = K21;
                o_at[n1*3+0] = at0; o_at[n1*3+1] = at1; o_at[n1*3+2] = at2;
            }
        }
    }
}

extern "C" void kernel_launch(void* const* d_in, const int* in_sizes, int n_in,
                              void* d_out, int out_size, void* d_ws, size_t ws_size,
                              hipStream_t stream) {
    const float* X         = (const float*)d_in[0];
    const int*   cids      = (const int*)  d_in[1];
    const float* lm        = (const float*)d_in[2];
    const float* Wq        = (const float*)d_in[3];
    const float* Wk        = (const float*)d_in[4];
    const float* Wv        = (const float*)d_in[5];
    const float* centroids = (const float*)d_in[6];
    float* out = (float*)d_out;
    const int N = in_sizes[0] / 3;

    const int nChunks = (N + 255) / 256;
    const int grid = nChunks < 1024 ? nChunks : 1024;   // 4 blocks/CU (32.8 KB LDS)
    fused4<<<grid, 256, 0, stream>>>(X, cids, lm, Wq, Wk, Wv, centroids, out, N, nChunks);
}

// Round 9
// 123.303 us; speedup vs baseline: 1.4382x; 1.4382x over previous
//
#include <hip/hip_runtime.h>
#include <math.h>

#define NUM_FREQS 10
#define EDIM 60            // 3 * 2 * NUM_FREQS
#define TRADEOFF 1.0f

typedef __attribute__((ext_vector_type(8))) short bf16x8;
typedef __attribute__((ext_vector_type(4))) float f32x4;

#define MFMA(a, b, c) __builtin_amdgcn_mfma_f32_16x16x32_bf16((a), (b), (c), 0, 0, 0)

// float -> bf16 (RNE) native cast
__device__ __forceinline__ short bfc(float f) {
    return __builtin_bit_cast(short, (__bf16)f);
}
// xor16 lane exchange via ds_swizzle (BitMode: offset = (xor<<10)|(or<<5)|and)
__device__ __forceinline__ float swz16(float x) {
    return __builtin_bit_cast(float,
        __builtin_amdgcn_ds_swizzle(__builtin_bit_cast(int, x), 0x401F));
}
// xor32 (crosses 32-lane halves)
__device__ __forceinline__ float sx32(float x) { return __shfl_xor(x, 32, 64); }

// Full posenc (prologue only, for centroids). Hardware sin/cos in revolutions.
__device__ __forceinline__ void posenc3(float x0, float x1, float x2, float* enc) {
    const float inv2pi = 0.15915494309189535f;
    float xs[3] = {x0, x1, x2};
#pragma unroll
    for (int d = 0; d < 3; ++d) {
        float xr = xs[d] * inv2pi;
#pragma unroll
        for (int l = 0; l < NUM_FREQS; ++l) {
            const float fr = __builtin_amdgcn_fractf(xr);
            enc[l*6 + d]     = __builtin_amdgcn_sinf(fr);
            enc[l*6 + 3 + d] = __builtin_amdgcn_cosf(fr);
            xr *= 2.0f;   // exact
        }
    }
}

// K-permutation: k' = 8b + 2i + c  (b = k-block 0..7, pair i 0..3, c: 0=sin 1=cos)
//   p = 4b + i (< 30), l = p/3, d = p%3  ->  original k = 6l + 3c + d.
// Lane's B-fragment (block b = kf*4+g) = 4 (sin,cos) pairs of angles x_d*2^l:
// computed in-register (ldexp + fract + v_sin/v_cos), no LDS staging of enc.
//
// sW rows r = 4c_cluster + ch (ch 0..2 = rgb, 3 = score), k'-basis, swizzled.
// MFMA m-subtile tg -> lane (g,l15) acc[rg] = cluster 4tg+g, channel rg, pt l15.
// Softmax (no max-sub: scores O(1), f32 exp safe) accumulated online in-lane
// over 4 row-quarters (acc[2][4] = 32 VGPRs live), then xor16+xor32 butterfly.
__global__ __launch_bounds__(256, 3) void fused5(
        const float* __restrict__ X,
        const int*   __restrict__ cluster_ids,
        const float* __restrict__ lm,      // [192, 60]
        const float* __restrict__ Wq,      // [5, 60]
        const float* __restrict__ Wk,      // [5, 60]
        const float* __restrict__ Wv,      // [3, 3]
        const float* __restrict__ cents,   // [64, 3]
        float* __restrict__ out,
        int N, int nChunks) {
    __shared__ __align__(16) unsigned short sW[256 * 64];  // 32 KB, k'-basis, swizzled

    const int tid  = threadIdx.x;
    const int lane = tid & 63;
    const int w    = tid >> 6;
    const int g    = (lane >> 4) & 3;
    const int l15  = lane & 15;

    // ================= prologue: build sW (once per block) =================
    {
        const int r = tid, ccl = r >> 2, ch = r & 3;
        float kq0 = 0.f, kq1 = 0.f, kq2 = 0.f, kq3 = 0.f, kq4 = 0.f;
        if (ch == 3) {
            float enc[EDIM];
            posenc3(cents[ccl*3+0], cents[ccl*3+1], cents[ccl*3+2], enc);
            const float isd = 0.4472135954999579f;  // 1/sqrt(5)
            float kk[5];
#pragma unroll
            for (int j = 0; j < 5; ++j) {
                float a = 0.f;
                for (int k = 0; k < EDIM; ++k) a = fmaf(enc[k], Wk[j*EDIM + k], a);
                kk[j] = a * isd;
            }
            kq0 = kk[0]; kq1 = kk[1]; kq2 = kk[2]; kq3 = kk[3]; kq4 = kk[4];
        }
        const float* lrow = lm + (3*ccl + (ch < 3 ? ch : 0)) * EDIM;
#pragma unroll
        for (int b = 0; b < 8; ++b) {
            bf16x8 v;
#pragma unroll
            for (int j = 0; j < 8; ++j) {
                const int p = b*4 + (j >> 1), cc = j & 1;
                float val = 0.f;
                if (p < 30) {
                    const int l = (p*11) >> 5, d = p - 3*l;
                    const int sig = 6*l + 3*cc + d;
                    if (ch < 3) val = lrow[sig];
                    else val = Wq[sig]*kq0 + Wq[60+sig]*kq1 + Wq[120+sig]*kq2
                             + Wq[180+sig]*kq3 + Wq[240+sig]*kq4;
                }
                v[j] = bfc(val);
            }
            *(bf16x8*)&sW[r*64 + (b ^ (r & 7))*8] = v;
        }
    }
    const float wv00 = Wv[0], wv01 = Wv[1], wv02 = Wv[2];
    const float wv10 = Wv[3], wv11 = Wv[4], wv12 = Wv[5];
    const float wv20 = Wv[6], wv21 = Wv[7], wv22 = Wv[8];

    __syncthreads();   // the ONLY block-wide barrier; sW read-only afterwards

    float* o_out = out;
    float* o_km  = out + (size_t)N * 3;
    float* o_at  = out + (size_t)N * 6;

    const float inv2pi = 0.15915494309189535f;
    const int slot0 = (g ^ (l15 & 7)) * 8;
    const int slot1 = ((4 + g) ^ (l15 & 7)) * 8;

    // ================= chunk loop (waves fully independent) =================
    for (int chunk = blockIdx.x; chunk < nChunks; chunk += gridDim.x) {
        const int base = (chunk << 8) + w*64;

#pragma unroll
        for (int h = 0; h < 2; ++h) {
            // ---- B-fragments for subtiles 2h, 2h+1, computed in-register
            bf16x8 bfr[2][2];
            int cid0, cid1, n0, n1;
#pragma unroll
            for (int u = 0; u < 2; ++u) {
                const int n = base + (2*h + u)*16 + l15;
                const int nc = n < N ? n : N - 1;
                if (u == 0) { n0 = n; cid0 = cluster_ids[nc]; }
                else        { n1 = n; cid1 = cluster_ids[nc]; }
                const float r0 = X[nc*3+0] * inv2pi;
                const float r1 = X[nc*3+1] * inv2pi;
                const float r2 = X[nc*3+2] * inv2pi;
#pragma unroll
                for (int kf = 0; kf < 2; ++kf) {
                    const int b = kf*4 + g;   // lane's k'-block
                    bf16x8 v;
#pragma unroll
                    for (int i = 0; i < 4; ++i) {
                        const int p = b*4 + i;
                        const int l = (p*11) >> 5;
                        const int d = p - 3*l;
                        const float rd = (d == 0) ? r0 : ((d == 1) ? r1 : r2);
                        const float t  = ldexpf(rd, l);
                        const float fr = __builtin_amdgcn_fractf(t);
                        const float sv = __builtin_amdgcn_sinf(fr);
                        const float cv = __builtin_amdgcn_cosf(fr);
                        const bool ok = (p < 30);
                        v[2*i]   = ok ? bfc(sv) : (short)0;
                        v[2*i+1] = ok ? bfc(cv) : (short)0;
                    }
                    bfr[u][kf] = v;
                }
            }

            // ---- online accumulators (no max-sub; scores are O(1))
            float S0=0.f, A00=0.f, A10=0.f, A20=0.f, K00=0.f, K10=0.f, K20=0.f;
            float S1=0.f, A01=0.f, A11=0.f, A21=0.f, K01=0.f, K11=0.f, K21=0.f;

            // 4 quarters of 4 m-subtiles: acc[2][4] = 32 VGPRs live (vs 64)
#pragma unroll
            for (int q = 0; q < 4; ++q) {
                f32x4 acc[2][4];
#pragma unroll
                for (int t = 0; t < 4; ++t) {
                    const int row = (q*4 + t)*16 + l15;
                    const bf16x8 a0 = *(const bf16x8*)&sW[row*64 + slot0];
                    const bf16x8 a1 = *(const bf16x8*)&sW[row*64 + slot1];
                    const f32x4 z = (f32x4){0.f, 0.f, 0.f, 0.f};
                    acc[0][t] = MFMA(a1, bfr[0][1], MFMA(a0, bfr[0][0], z));
                    acc[1][t] = MFMA(a1, bfr[1][1], MFMA(a0, bfr[1][0], z));
                }
#pragma unroll
                for (int t = 0; t < 4; ++t) {
                    const int cl = 4*(q*4 + t) + g;   // this lane's cluster
                    {
                        const float e = __expf(acc[0][t][3]);
                        S0 += e;
                        A00 = fmaf(e, acc[0][t][0], A00);
                        A10 = fmaf(e, acc[0][t][1], A10);
                        A20 = fmaf(e, acc[0][t][2], A20);
                        const bool sel = (cid0 == cl);
                        K00 = sel ? acc[0][t][0] : K00;
                        K10 = sel ? acc[0][t][1] : K10;
                        K20 = sel ? acc[0][t][2] : K20;
                    }
                    {
                        const float e = __expf(acc[1][t][3]);
                        S1 += e;
                        A01 = fmaf(e, acc[1][t][0], A01);
                        A11 = fmaf(e, acc[1][t][1], A11);
                        A21 = fmaf(e, acc[1][t][2], A21);
                        const bool sel = (cid1 == cl);
                        K01 = sel ? acc[1][t][0] : K01;
                        K11 = sel ? acc[1][t][1] : K11;
                        K21 = sel ? acc[1][t][2] : K21;
                    }
                }
            }

            // ---- cross-g butterfly (xor16 swizzle + xor32 shfl), then store
            S0 += swz16(S0); A00 += swz16(A00); A10 += swz16(A10); A20 += swz16(A20);
            K00 += swz16(K00); K10 += swz16(K10); K20 += swz16(K20);
            S0 += sx32(S0);  A00 += sx32(A00);  A10 += sx32(A10);  A20 += sx32(A20);
            K00 += sx32(K00); K10 += sx32(K10); K20 += sx32(K20);

            S1 += swz16(S1); A01 += swz16(A01); A11 += swz16(A11); A21 += swz16(A21);
            K01 += swz16(K01); K11 += swz16(K11); K21 += swz16(K21);
            S1 += sx32(S1);  A01 += sx32(A01);  A11 += sx32(A11);  A21 += sx32(A21);
            K01 += sx32(K01); K11 += sx32(K11); K21 += sx32(K21);

            if (g == 0 && n0 < N) {
                const float inv = 1.0f / S0;
                const float u0 = A00*inv, u1 = A10*inv, u2 = A20*inv;
                const float at0 = wv00*u0 + wv01*u1 + wv02*u2;
                const float at1 = wv10*u0 + wv11*u1 + wv12*u2;
                const float at2 = wv20*u0 + wv21*u1 + wv22*u2;
                o_out[n0*3+0] = K00*TRADEOFF + at0*(1.0f - TRADEOFF);
                o_out[n0*3+1] = K10*TRADEOFF + at1*(1.0f - TRADEOFF);
                o_out[n0*3+2] = K20*TRADEOFF + at2*(1.0f - TRADEOFF);
                o_km[n0*3+0] = K00; o_km[n0*3+1] = K10; o_km[n0*3+2] = K20;
                o_at[n0*3+0] = at0; o_at[n0*3+1] = at1; o_at[n0*3+2] = at2;
            }
            if (g == 0 && n1 < N) {
                const float inv = 1.0f / S1;
                const float u0 = A01*inv, u1 = A11*inv, u2 = A21*inv;
                const float at0 = wv00*u0 + wv01*u1 + wv02*u2;
                const float at1 = wv10*u0 + wv11*u1 + wv12*u2;
                const float at2 = wv20*u0 + wv21*u1 + wv22*u2;
                o_out[n1*3+0] = K01*TRADEOFF + at0*(1.0f - TRADEOFF);
                o_out[n1*3+1] = K11*TRADEOFF + at1*(1.0f - TRADEOFF);
                o_out[n1*3+2] = K21*TRADEOFF + at2*(1.0f - TRADEOFF);
                o_km[n1*3+0] = K01; o_km[n1*3+1] = K11; o_km[n1*3+2] = K21;
                o_at[n1*3+0] = at0; o_at[n1*3+1] = at1; o_at[n1*3+2] = at2;
            }
        }
    }
}

extern "C" void kernel_launch(void* const* d_in, const int* in_sizes, int n_in,
                              void* d_out, int out_size, void* d_ws, size_t ws_size,
                              hipStream_t stream) {
    const float* X         = (const float*)d_in[0];
    const int*   cids      = (const int*)  d_in[1];
    const float* lm        = (const float*)d_in[2];
    const float* Wq        = (const float*)d_in[3];
    const float* Wk        = (const float*)d_in[4];
    const float* Wv        = (const float*)d_in[5];
    const float* centroids = (const float*)d_in[6];
    float* out = (float*)d_out;
    const int N = in_sizes[0] / 3;

    const int nChunks = (N + 255) / 256;
    const int grid = nChunks < 768 ? nChunks : 768;   // 3 blocks/CU (32.8 KB LDS, 12 waves)
    fused5<<<grid, 256, 0, stream>>>(X, cids, lm, Wq, Wk, Wv, centroids, out, N, nChunks);
}

// Round 11
// 121.000 us; speedup vs baseline: 1.4656x; 1.0190x over previous
//
#include <hip/hip_runtime.h>
#include <math.h>

#define NUM_FREQS 10
#define EDIM 60            // 3 * 2 * NUM_FREQS
#define TRADEOFF 1.0f

typedef __attribute__((ext_vector_type(8))) short bf16x8;
typedef __attribute__((ext_vector_type(4))) float f32x4;

#define MFMA(a, b, c) __builtin_amdgcn_mfma_f32_16x16x32_bf16((a), (b), (c), 0, 0, 0)

// float -> bf16 (RNE) native cast
__device__ __forceinline__ short bfc(float f) {
    return __builtin_bit_cast(short, (__bf16)f);
}
// xor16 lane exchange via ds_swizzle (BitMode: offset = (xor<<10)|(or<<5)|and)
__device__ __forceinline__ float swz16(float x) {
    return __builtin_bit_cast(float,
        __builtin_amdgcn_ds_swizzle(__builtin_bit_cast(int, x), 0x401F));
}
// xor32 (crosses 32-lane halves)
__device__ __forceinline__ float sx32(float x) { return __shfl_xor(x, 32, 64); }

// Full posenc (prologue only, for centroids). Hardware sin/cos in revolutions.
__device__ __forceinline__ void posenc3(float x0, float x1, float x2, float* enc) {
    const float inv2pi = 0.15915494309189535f;
    float xs[3] = {x0, x1, x2};
#pragma unroll
    for (int d = 0; d < 3; ++d) {
        float xr = xs[d] * inv2pi;
#pragma unroll
        for (int l = 0; l < NUM_FREQS; ++l) {
            const float fr = __builtin_amdgcn_fractf(xr);
            enc[l*6 + d]     = __builtin_amdgcn_sinf(fr);
            enc[l*6 + 3 + d] = __builtin_amdgcn_cosf(fr);
            xr *= 2.0f;   // exact
        }
    }
}

// K-permutation: k' = 8b + 2i + c  (b = k-block 0..7, pair i 0..3, c: 0=sin 1=cos)
//   p = 4b + i (< 30), l = p/3, d = p%3  ->  original k = 6l + 3c + d.
// Lane's B-fragment (block b = kf*4+g) = 4 (sin,cos) pairs of angles x_d*2^l:
// computed in-register (ldexp + fract + v_sin/v_cos), no LDS staging of enc.
//
// sW rows r = 4c_cluster + ch (ch 0..2 = rgb, 3 = score), k'-basis, swizzled.
// Score rows pre-scaled by log2(e) so softmax uses raw v_exp_f32 (2^x):
//   2^(s*log2e) == e^s; ratios in the softmax are identical.
// MFMA m-subtile tg -> lane (g,l15) acc[rg] = cluster 4tg+g, channel rg, pt l15.
// Softmax (no max-sub: scores O(1), f32 exp safe) accumulated online in-lane
// over 4 row-quarters (acc[2][4] = 32 regs live), then xor16+xor32 butterfly.
//
// NO waves-per-EU launch-bounds cap: rounds 8/9 proved capping the unified
// VGPR+AGPR budget below ~170 forces scratch spill (88-346 MB HBM traffic).
__global__ __launch_bounds__(256) void fused6(
        const float* __restrict__ X,
        const int*   __restrict__ cluster_ids,
        const float* __restrict__ lm,      // [192, 60]
        const float* __restrict__ Wq,      // [5, 60]
        const float* __restrict__ Wk,      // [5, 60]
        const float* __restrict__ Wv,      // [3, 3]
        const float* __restrict__ cents,   // [64, 3]
        float* __restrict__ out,
        int N, int nChunks) {
    __shared__ __align__(16) unsigned short sW[256 * 64];  // 32 KB, k'-basis, swizzled

    const int tid  = threadIdx.x;
    const int lane = tid & 63;
    const int w    = tid >> 6;
    const int g    = (lane >> 4) & 3;
    const int l15  = lane & 15;

    // ================= prologue: build sW (once per block) =================
    {
        const int r = tid, ccl = r >> 2, ch = r & 3;
        float kq0 = 0.f, kq1 = 0.f, kq2 = 0.f, kq3 = 0.f, kq4 = 0.f;
        if (ch == 3) {
            float enc[EDIM];
            posenc3(cents[ccl*3+0], cents[ccl*3+1], cents[ccl*3+2], enc);
            // 1/sqrt(5) * log2(e): fold softmax's exp->exp2 conversion into W
            const float isd = 0.4472135954999579f * 1.4426950408889634f;
            float kk[5];
#pragma unroll
            for (int j = 0; j < 5; ++j) {
                float a = 0.f;
                for (int k = 0; k < EDIM; ++k) a = fmaf(enc[k], Wk[j*EDIM + k], a);
                kk[j] = a * isd;
            }
            kq0 = kk[0]; kq1 = kk[1]; kq2 = kk[2]; kq3 = kk[3]; kq4 = kk[4];
        }
        const float* lrow = lm + (3*ccl + (ch < 3 ? ch : 0)) * EDIM;
#pragma unroll
        for (int b = 0; b < 8; ++b) {
            bf16x8 v;
#pragma unroll
            for (int j = 0; j < 8; ++j) {
                const int p = b*4 + (j >> 1), cc = j & 1;
                float val = 0.f;
                if (p < 30) {
                    const int l = (p*11) >> 5, d = p - 3*l;
                    const int sig = 6*l + 3*cc + d;
                    if (ch < 3) val = lrow[sig];
                    else val = Wq[sig]*kq0 + Wq[60+sig]*kq1 + Wq[120+sig]*kq2
                             + Wq[180+sig]*kq3 + Wq[240+sig]*kq4;
                }
                v[j] = bfc(val);
            }
            *(bf16x8*)&sW[r*64 + (b ^ (r & 7))*8] = v;
        }
    }
    const float wv00 = Wv[0], wv01 = Wv[1], wv02 = Wv[2];
    const float wv10 = Wv[3], wv11 = Wv[4], wv12 = Wv[5];
    const float wv20 = Wv[6], wv21 = Wv[7], wv22 = Wv[8];

    __syncthreads();   // the ONLY block-wide barrier; sW read-only afterwards

    float* o_out = out;
    float* o_km  = out + (size_t)N * 3;
    float* o_at  = out + (size_t)N * 6;

    const float inv2pi = 0.15915494309189535f;
    const int slot0 = (g ^ (l15 & 7)) * 8;
    const int slot1 = ((4 + g) ^ (l15 & 7)) * 8;

    // ================= chunk loop (waves fully independent) =================
    for (int chunk = blockIdx.x; chunk < nChunks; chunk += gridDim.x) {
        const int base = (chunk << 8) + w*64;

#pragma unroll
        for (int h = 0; h < 2; ++h) {
            // ---- B-fragments for subtiles 2h, 2h+1, computed in-register
            bf16x8 bfr[2][2];
            int cid0, cid1, n0, n1;
#pragma unroll
            for (int u = 0; u < 2; ++u) {
                const int n = base + (2*h + u)*16 + l15;
                const int nc = n < N ? n : N - 1;
                if (u == 0) { n0 = n; cid0 = cluster_ids[nc]; }
                else        { n1 = n; cid1 = cluster_ids[nc]; }
                const float r0 = X[nc*3+0] * inv2pi;
                const float r1 = X[nc*3+1] * inv2pi;
                const float r2 = X[nc*3+2] * inv2pi;
#pragma unroll
                for (int kf = 0; kf < 2; ++kf) {
                    const int b = kf*4 + g;   // lane's k'-block
                    bf16x8 v;
#pragma unroll
                    for (int i = 0; i < 4; ++i) {
                        const int p = b*4 + i;
                        const int l = (p*11) >> 5;
                        const int d = p - 3*l;
                        const float rd = (d == 0) ? r0 : ((d == 1) ? r1 : r2);
                        const float t  = ldexpf(rd, l);
                        const float fr = __builtin_amdgcn_fractf(t);
                        const float sv = __builtin_amdgcn_sinf(fr);
                        const float cv = __builtin_amdgcn_cosf(fr);
                        const bool ok = (p < 30);
                        v[2*i]   = ok ? bfc(sv) : (short)0;
                        v[2*i+1] = ok ? bfc(cv) : (short)0;
                    }
                    bfr[u][kf] = v;
                }
            }

            // ---- online accumulators (no max-sub; scores are O(1))
            float S0=0.f, A00=0.f, A10=0.f, A20=0.f, K00=0.f, K10=0.f, K20=0.f;
            float S1=0.f, A01=0.f, A11=0.f, A21=0.f, K01=0.f, K11=0.f, K21=0.f;

            // 4 quarters of 4 m-subtiles: acc[2][4] = 32 regs live
#pragma unroll
            for (int q = 0; q < 4; ++q) {
                f32x4 acc[2][4];
#pragma unroll
                for (int t = 0; t < 4; ++t) {
                    const int row = (q*4 + t)*16 + l15;
                    const bf16x8 a0 = *(const bf16x8*)&sW[row*64 + slot0];
                    const bf16x8 a1 = *(const bf16x8*)&sW[row*64 + slot1];
                    const f32x4 z = (f32x4){0.f, 0.f, 0.f, 0.f};
                    acc[0][t] = MFMA(a1, bfr[0][1], MFMA(a0, bfr[0][0], z));
                    acc[1][t] = MFMA(a1, bfr[1][1], MFMA(a0, bfr[1][0], z));
                }
#pragma unroll
                for (int t = 0; t < 4; ++t) {
                    const int cl = 4*(q*4 + t) + g;   // this lane's cluster
                    {
                        const float e = __builtin_amdgcn_exp2f(acc[0][t][3]);
                        S0 += e;
                        A00 = fmaf(e, acc[0][t][0], A00);
                        A10 = fmaf(e, acc[0][t][1], A10);
                        A20 = fmaf(e, acc[0][t][2], A20);
                        const bool sel = (cid0 == cl);
                        K00 = sel ? acc[0][t][0] : K00;
                        K10 = sel ? acc[0][t][1] : K10;
                        K20 = sel ? acc[0][t][2] : K20;
                    }
                    {
                        const float e = __builtin_amdgcn_exp2f(acc[1][t][3]);
                        S1 += e;
                        A01 = fmaf(e, acc[1][t][0], A01);
                        A11 = fmaf(e, acc[1][t][1], A11);
                        A21 = fmaf(e, acc[1][t][2], A21);
                        const bool sel = (cid1 == cl);
                        K01 = sel ? acc[1][t][0] : K01;
                        K11 = sel ? acc[1][t][1] : K11;
                        K21 = sel ? acc[1][t][2] : K21;
                    }
                }
            }

            // ---- cross-g butterfly (xor16 swizzle + xor32 shfl), then store
            S0 += swz16(S0); A00 += swz16(A00); A10 += swz16(A10); A20 += swz16(A20);
            K00 += swz16(K00); K10 += swz16(K10); K20 += swz16(K20);
            S0 += sx32(S0);  A00 += sx32(A00);  A10 += sx32(A10);  A20 += sx32(A20);
            K00 += sx32(K00); K10 += sx32(K10); K20 += sx32(K20);

            S1 += swz16(S1); A01 += swz16(A01); A11 += swz16(A11); A21 += swz16(A21);
            K01 += swz16(K01); K11 += swz16(K11); K21 += swz16(K21);
            S1 += sx32(S1);  A01 += sx32(A01);  A11 += sx32(A11);  A21 += sx32(A21);
            K01 += sx32(K01); K11 += sx32(K11); K21 += sx32(K21);

            if (g == 0 && n0 < N) {
                const float inv = 1.0f / S0;
                const float u0 = A00*inv, u1 = A10*inv, u2 = A20*inv;
                const float at0 = wv00*u0 + wv01*u1 + wv02*u2;
                const float at1 = wv10*u0 + wv11*u1 + wv12*u2;
                const float at2 = wv20*u0 + wv21*u1 + wv22*u2;
                o_out[n0*3+0] = K00*TRADEOFF + at0*(1.0f - TRADEOFF);
                o_out[n0*3+1] = K10*TRADEOFF + at1*(1.0f - TRADEOFF);
                o_out[n0*3+2] = K20*TRADEOFF + at2*(1.0f - TRADEOFF);
                o_km[n0*3+0] = K00; o_km[n0*3+1] = K10; o_km[n0*3+2] = K20;
                o_at[n0*3+0] = at0; o_at[n0*3+1] = at1; o_at[n0*3+2] = at2;
            }
            if (g == 0 && n1 < N) {
                const float inv = 1.0f / S1;
                const float u0 = A01*inv, u1 = A11*inv, u2 = A21*inv;
                const float at0 = wv00*u0 + wv01*u1 + wv02*u2;
                const float at1 = wv10*u0 + wv11*u1 + wv12*u2;
                const float at2 = wv20*u0 + wv21*u1 + wv22*u2;
                o_out[n1*3+0] = K01*TRADEOFF + at0*(1.0f - TRADEOFF);
                o_out[n1*3+1] = K11*TRADEOFF + at1*(1.0f - TRADEOFF);
                o_out[n1*3+2] = K21*TRADEOFF + at2*(1.0f - TRADEOFF);
                o_km[n1*3+0] = K01; o_km[n1*3+1] = K11; o_km[n1*3+2] = K21;
                o_at[n1*3+0] = at0; o_at[n1*3+1] = at1; o_at[n1*3+2] = at2;
            }
        }
    }
}

extern "C" void kernel_launch(void* const* d_in, const int* in_sizes, int n_in,
                              void* d_out, int out_size, void* d_ws, size_t ws_size,
                              hipStream_t stream) {
    const float* X         = (const float*)d_in[0];
    const int*   cids      = (const int*)  d_in[1];
    const float* lm        = (const float*)d_in[2];
    const float* Wq        = (const float*)d_in[3];
    const float* Wk        = (const float*)d_in[4];
    const float* Wv        = (const float*)d_in[5];
    const float* centroids = (const float*)d_in[6];
    float* out = (float*)d_out;
    const int N = in_sizes[0] / 3;

    const int nChunks = (N + 255) / 256;
    const int grid = nChunks < 768 ? nChunks : 768;   // 3 blocks/CU target
    fused6<<<grid, 256, 0, stream>>>(X, cids, lm, Wq, Wk, Wv, centroids, out, N, nChunks);
}